// Round 1
// baseline (146.362 us; speedup 1.0000x reference)
//
#include <hip/hip_runtime.h>
#include <hip/hip_fp16.h>
#include <hip/hip_cooperative_groups.h>

// DistMult forward scoring: score[e] = sum_d h[src,d] * fwd_rel[et,d] * h[dst,d]
// E=640000, D=128, fp32 in/out.
//
// R5: single fused cooperative kernel (convert fp32->fp16 into ws, grid.sync,
// then gather+score). Dot math via v_pk_mul_f16 + v_fma_mix_f32 (mixed f16
// inputs, f32 accumulate) cutting dot VALU ~3x vs scalar cvt path. Indices
// for the next iteration are software-prefetched so the cold HBM idx load
// overlaps the current iteration's L2 gathers + compute.

typedef unsigned short u16;
typedef _Float16 h2v __attribute__((ext_vector_type(2)));

constexpr int EMB_DIM  = 128;
constexpr int MAX_RELS = 500;
constexpr int BLOCKS   = 256;    // 1 per CU (coop co-residency guaranteed)
constexpr int THREADS  = 1024;   // 64 teams of 16 lanes

namespace cg = cooperative_groups;

// ---- fp32 -> fp16 pack, 8 floats per slot ----
__device__ __forceinline__ void convert_slot(const float* __restrict__ s,
                                             u16* __restrict__ d, int j) {
    float4 lo = reinterpret_cast<const float4*>(s)[j * 2];
    float4 hi = reinterpret_cast<const float4*>(s)[j * 2 + 1];
    u16 u0 = __half_as_ushort(__float2half(lo.x));
    u16 u1 = __half_as_ushort(__float2half(lo.y));
    u16 u2 = __half_as_ushort(__float2half(lo.z));
    u16 u3 = __half_as_ushort(__float2half(lo.w));
    u16 u4 = __half_as_ushort(__float2half(hi.x));
    u16 u5 = __half_as_ushort(__float2half(hi.y));
    u16 u6 = __half_as_ushort(__float2half(hi.z));
    u16 u7 = __half_as_ushort(__float2half(hi.w));
    uint4 v;
    v.x = (unsigned)u0 | ((unsigned)u1 << 16);
    v.y = (unsigned)u2 | ((unsigned)u3 << 16);
    v.z = (unsigned)u4 | ((unsigned)u5 << 16);
    v.w = (unsigned)u6 | ((unsigned)u7 << 16);
    reinterpret_cast<uint4*>(d)[j] = v;
}

// fallback prologue if cooperative launch is unavailable
__global__ __launch_bounds__(256) void convert_fp16_kernel(
    const float* __restrict__ a, u16* __restrict__ a16, int n_a8,
    const float* __restrict__ b, u16* __restrict__ b16, int n_b8)
{
    const int total = n_a8 + n_b8;
    for (int i = blockIdx.x * blockDim.x + threadIdx.x; i < total;
         i += gridDim.x * blockDim.x) {
        if (i < n_a8) convert_slot(a, a16, i);
        else          convert_slot(b, b16, i - n_a8);
    }
}

// 8-element triple product, f32 accumulate.
// t = a*c in packed fp16 (v_pk_mul_f16); then (float)t * (float)b + acc
// folds to v_fma_mix_f32 (2 instrs/k). ~12 VALU per dot8 vs 40 scalar-cvt.
__device__ __forceinline__ float dot8(uint4 A, uint4 B, uint4 C, float acc) {
    const h2v* a = reinterpret_cast<const h2v*>(&A);
    const h2v* b = reinterpret_cast<const h2v*>(&B);
    const h2v* c = reinterpret_cast<const h2v*>(&C);
    #pragma unroll
    for (int k = 0; k < 4; ++k) {
        h2v t = a[k] * c[k];                    // v_pk_mul_f16
        acc += (float)t.x * (float)b[k].x;      // v_fma_mix_f32
        acc += (float)t.y * (float)b[k].y;      // v_fma_mix_f32
    }
    return acc;
}

__global__ __launch_bounds__(THREADS) void distmult_fused_kernel(
    const float* __restrict__ hf,    // [n_nodes][128] fp32
    const float* __restrict__ wf,    // [n_rels][128] fp32
    u16*         __restrict__ h16,   // ws: fp16 h
    u16*         __restrict__ w16,   // ws: fp16 fwd_rel
    const int*   __restrict__ src,
    const int*   __restrict__ dst,
    const int*   __restrict__ etype,
    float*       __restrict__ out,
    int n_h8, int n_w8, int n_edges, int n_rels, int do_convert)
{
    // ---- phase 1: fp32 -> fp16 into workspace ----
    if (do_convert) {
        const int total = n_h8 + n_w8;
        for (int i = blockIdx.x * blockDim.x + threadIdx.x; i < total;
             i += gridDim.x * blockDim.x) {
            if (i < n_h8) convert_slot(hf, h16, i);
            else          convert_slot(wf, w16, i - n_h8);
        }
        cg::this_grid().sync();   // device-scope fence + grid barrier
    }

    // ---- phase 2: stage fwd_rel fp16 into LDS ----
    __shared__ u16 w_lds[MAX_RELS * EMB_DIM];   // 128 KB
    {
        const int slots = n_rels * (EMB_DIM / 8);
        for (int s = threadIdx.x; s < slots; s += THREADS)
            reinterpret_cast<uint4*>(w_lds)[s] =
                reinterpret_cast<const uint4*>(w16)[s];
    }
    __syncthreads();

    const int team = threadIdx.x >> 4;   // 64 teams
    const int lane = threadIdx.x & 15;

    const uint4* hp = reinterpret_cast<const uint4*>(h16) + lane;  // +16/row
    const uint4* wl = reinterpret_cast<const uint4*>(w_lds) + lane;

    const int stride = BLOCKS * (THREADS / 16) * 4;   // 65536 edges/pass

    int e0 = (blockIdx.x * (THREADS / 16) + team) * 4;
    int4 s4, d4, t4;
    bool valid = (e0 + 3 < n_edges);
    if (valid) {
        s4 = *reinterpret_cast<const int4*>(src   + e0);
        d4 = *reinterpret_cast<const int4*>(dst   + e0);
        t4 = *reinterpret_cast<const int4*>(etype + e0);
    }

    while (valid) {
        // software prefetch: next iteration's indices (HBM latency hides
        // under this iteration's gathers + compute)
        const int e1 = e0 + stride;
        const bool nvalid = (e1 + 3 < n_edges);
        int4 ns = s4, nd = d4, nt = t4;
        if (nvalid) {
            ns = *reinterpret_cast<const int4*>(src   + e1);
            nd = *reinterpret_cast<const int4*>(dst   + e1);
            nt = *reinterpret_cast<const int4*>(etype + e1);
        }

        // 8 L2 gathers: full 256 B fp16 rows, 16 B/lane (coalesced per team)
        const uint4 a0 = hp[(size_t)(unsigned)s4.x * 16];
        const uint4 a1 = hp[(size_t)(unsigned)s4.y * 16];
        const uint4 a2 = hp[(size_t)(unsigned)s4.z * 16];
        const uint4 a3 = hp[(size_t)(unsigned)s4.w * 16];
        const uint4 c0 = hp[(size_t)(unsigned)d4.x * 16];
        const uint4 c1 = hp[(size_t)(unsigned)d4.y * 16];
        const uint4 c2 = hp[(size_t)(unsigned)d4.z * 16];
        const uint4 c3 = hp[(size_t)(unsigned)d4.w * 16];
        // 4 LDS reads for w
        const uint4 b0 = wl[(unsigned)t4.x * 16];
        const uint4 b1 = wl[(unsigned)t4.y * 16];
        const uint4 b2 = wl[(unsigned)t4.z * 16];
        const uint4 b3 = wl[(unsigned)t4.w * 16];

        float acc0 = dot8(a0, b0, c0, 0.f);
        float acc1 = dot8(a1, b1, c1, 0.f);
        float acc2 = dot8(a2, b2, c2, 0.f);
        float acc3 = dot8(a3, b3, c3, 0.f);

        #pragma unroll
        for (int off = 8; off > 0; off >>= 1) {
            acc0 += __shfl_down(acc0, off, 16);
            acc1 += __shfl_down(acc1, off, 16);
            acc2 += __shfl_down(acc2, off, 16);
            acc3 += __shfl_down(acc3, off, 16);
        }
        if (lane == 0)
            *reinterpret_cast<float4*>(out + e0) =
                make_float4(acc0, acc1, acc2, acc3);

        e0 = e1; s4 = ns; d4 = nd; t4 = nt; valid = nvalid;
    }

    // tail: at most one partial quad per team
    for (int e = e0; e < n_edges && e < e0 + 4; ++e) {
        const uint4 a = hp[(size_t)(unsigned)src[e]   * 16];
        const uint4 c = hp[(size_t)(unsigned)dst[e]   * 16];
        const uint4 b = wl[(unsigned)etype[e] * 16];
        float acc = dot8(a, b, c, 0.f);
        #pragma unroll
        for (int off = 8; off > 0; off >>= 1)
            acc += __shfl_down(acc, off, 16);
        if (lane == 0) out[e] = acc;
    }
}

// fallback: fp32 direct (R0-style) if ws too small or n_rels > MAX_RELS
__global__ __launch_bounds__(256) void distmult_score_kernel(
    const float* __restrict__ h,
    const int*   __restrict__ src,
    const int*   __restrict__ dst,
    const int*   __restrict__ etype,
    const float* __restrict__ fwd_rel,
    float*       __restrict__ out,
    int n_edges)
{
    const int tid  = blockIdx.x * blockDim.x + threadIdx.x;
    const int lane = threadIdx.x & 63;
    const int half = lane >> 5;
    const int sub  = lane & 31;
    const int edge = (tid >> 6) * 2 + half;
    if (edge >= n_edges) return;

    const int s = src[edge];
    const int d = dst[edge];
    const int e = etype[edge];

    const float4 a = reinterpret_cast<const float4*>(h       + (size_t)s * EMB_DIM)[sub];
    const float4 b = reinterpret_cast<const float4*>(fwd_rel + (size_t)e * EMB_DIM)[sub];
    const float4 c = reinterpret_cast<const float4*>(h       + (size_t)d * EMB_DIM)[sub];

    float acc = a.x*b.x*c.x + a.y*b.y*c.y + a.z*b.z*c.z + a.w*b.w*c.w;
    #pragma unroll
    for (int off = 16; off > 0; off >>= 1)
        acc += __shfl_down(acc, off, 32);
    if (sub == 0) out[edge] = acc;
}

extern "C" void kernel_launch(void* const* d_in, const int* in_sizes, int n_in,
                              void* d_out, int out_size, void* d_ws, size_t ws_size,
                              hipStream_t stream) {
    const float* h       = (const float*)d_in[0];
    const int*   src     = (const int*)d_in[1];
    const int*   dst     = (const int*)d_in[2];
    const int*   etype   = (const int*)d_in[3];
    const float* fwd_rel = (const float*)d_in[4];
    float* out = (float*)d_out;

    const int n_edges = in_sizes[1];
    const int n_h     = in_sizes[0];              // n_nodes*128
    const int n_w     = in_sizes[4];              // n_rels*128
    const int n_rels  = n_w / EMB_DIM;
    const size_t need = (size_t)(n_h + n_w) * sizeof(u16);

    if (ws_size >= need && n_rels <= MAX_RELS &&
        (n_h % 8) == 0 && (n_w % 8) == 0) {
        u16* h16 = (u16*)d_ws;
        u16* w16 = h16 + n_h;
        int n_h8 = n_h / 8, n_w8 = n_w / 8;
        int ne = n_edges, nr = n_rels, do_conv = 1;
        const float* hf = h; const float* wf = fwd_rel;
        const int* sp = src; const int* dp = dst; const int* tp = etype;
        float* op = out;

        void* args[] = { &hf, &wf, &h16, &w16, &sp, &dp, &tp, &op,
                         &n_h8, &n_w8, &ne, &nr, &do_conv };
        hipError_t err = hipLaunchCooperativeKernel(
            (const void*)distmult_fused_kernel, dim3(BLOCKS), dim3(THREADS),
            args, 0, stream);

        if (err != hipSuccess) {
            // non-cooperative fallback: separate convert, then fused kernel
            // with do_convert=0 (never touches grid.sync)
            const int cgrid = (n_h8 + n_w8 + 255) / 256;
            convert_fp16_kernel<<<cgrid, 256, 0, stream>>>(
                h, h16, n_h8, fwd_rel, w16, n_w8);
            distmult_fused_kernel<<<BLOCKS, THREADS, 0, stream>>>(
                h, fwd_rel, h16, w16, src, dst, etype, out,
                n_h8, n_w8, n_edges, n_rels, 0);
        }
    } else {
        const int grid = (n_edges + 7) / 8;
        distmult_score_kernel<<<grid, 256, 0, stream>>>(
            h, src, dst, etype, fwd_rel, out, n_edges);
    }
}

// Round 2
// 133.850 us; speedup vs baseline: 1.0935x; 1.0935x over previous
//
#include <hip/hip_runtime.h>
#include <hip/hip_fp16.h>

// DistMult forward scoring: score[e] = sum_d h[src,d] * fwd_rel[et,d] * h[dst,d]
// E=640000, D=128, fp32 in/out.
//
// R6: revert R5's cooperative fusion (coop launch cost ~50us of dispatch
// overhead in the timed path). Back to two plain launches (graph-friendly).
// Main kernel is latency-bound (R5 counters: HBM 5%, VALUBusy 15.7%,
// occupancy 37.8%, 0 bank conflicts) -> attack exposed L2 gather latency
// with ILP: 8 edges/team/iter (16 outstanding 256B row-gathers/thread),
// next-iter index prefetch, v_pk_mul_f16 + v_fma_mix_f32 dot math.
// __launch_bounds__(1024,4) pins VGPR<=128 so unroll can't drop occupancy.

typedef unsigned short u16;
typedef _Float16 h2v __attribute__((ext_vector_type(2)));

constexpr int EMB_DIM  = 128;
constexpr int MAX_RELS = 500;
constexpr int BLOCKS   = 256;    // 1 per CU
constexpr int THREADS  = 1024;   // 64 teams of 16 lanes
constexpr int EPT      = 8;      // edges per team per iteration

// ---- fp32 -> fp16 pack, 8 floats per slot ----
__device__ __forceinline__ void convert_slot(const float* __restrict__ s,
                                             u16* __restrict__ d, int j) {
    float4 lo = reinterpret_cast<const float4*>(s)[j * 2];
    float4 hi = reinterpret_cast<const float4*>(s)[j * 2 + 1];
    u16 u0 = __half_as_ushort(__float2half(lo.x));
    u16 u1 = __half_as_ushort(__float2half(lo.y));
    u16 u2 = __half_as_ushort(__float2half(lo.z));
    u16 u3 = __half_as_ushort(__float2half(lo.w));
    u16 u4 = __half_as_ushort(__float2half(hi.x));
    u16 u5 = __half_as_ushort(__float2half(hi.y));
    u16 u6 = __half_as_ushort(__float2half(hi.z));
    u16 u7 = __half_as_ushort(__float2half(hi.w));
    uint4 v;
    v.x = (unsigned)u0 | ((unsigned)u1 << 16);
    v.y = (unsigned)u2 | ((unsigned)u3 << 16);
    v.z = (unsigned)u4 | ((unsigned)u5 << 16);
    v.w = (unsigned)u6 | ((unsigned)u7 << 16);
    reinterpret_cast<uint4*>(d)[j] = v;
}

__global__ __launch_bounds__(256) void convert_fp16_kernel(
    const float* __restrict__ a, u16* __restrict__ a16, int n_a8,
    const float* __restrict__ b, u16* __restrict__ b16, int n_b8)
{
    const int total = n_a8 + n_b8;
    for (int i = blockIdx.x * blockDim.x + threadIdx.x; i < total;
         i += gridDim.x * blockDim.x) {
        if (i < n_a8) convert_slot(a, a16, i);
        else          convert_slot(b, b16, i - n_a8);
    }
}

// 8-element triple product, f32 accumulate.
// t = a*c packed fp16 (v_pk_mul_f16); (float)t * (float)b + acc folds to
// v_fma_mix_f32. ~12 VALU per dot8.
__device__ __forceinline__ float dot8(uint4 A, uint4 B, uint4 C) {
    const h2v* a = reinterpret_cast<const h2v*>(&A);
    const h2v* b = reinterpret_cast<const h2v*>(&B);
    const h2v* c = reinterpret_cast<const h2v*>(&C);
    float acc = 0.f;
    #pragma unroll
    for (int k = 0; k < 4; ++k) {
        h2v t = a[k] * c[k];                    // v_pk_mul_f16
        acc += (float)t.x * (float)b[k].x;      // v_fma_mix_f32
        acc += (float)t.y * (float)b[k].y;      // v_fma_mix_f32
    }
    return acc;
}

__device__ __forceinline__ float team_reduce16(float acc) {
    #pragma unroll
    for (int off = 8; off > 0; off >>= 1)
        acc += __shfl_down(acc, off, 16);
    return acc;
}

__global__ __launch_bounds__(THREADS, 4) void distmult_fp16_kernel(
    const u16* __restrict__ h16,     // [n_nodes][128] fp16
    const int* __restrict__ src,
    const int* __restrict__ dst,
    const int* __restrict__ etype,
    const u16* __restrict__ w16,     // [n_rels][128] fp16
    float*     __restrict__ out,
    int n_edges, int n_rels)
{
    __shared__ u16 w_lds[MAX_RELS * EMB_DIM];   // 128 KB

    // stage fwd_rel fp16 into LDS (linear, coalesced uint4)
    {
        const int slots = n_rels * (EMB_DIM / 8);
        for (int s = threadIdx.x; s < slots; s += THREADS)
            reinterpret_cast<uint4*>(w_lds)[s] =
                reinterpret_cast<const uint4*>(w16)[s];
    }
    __syncthreads();

    const int team = threadIdx.x >> 4;   // 64 teams
    const int lane = threadIdx.x & 15;

    const uint4* hp = reinterpret_cast<const uint4*>(h16) + lane;  // +16/row
    const uint4* wl = reinterpret_cast<const uint4*>(w_lds) + lane;

    const int stride = BLOCKS * (THREADS / 16) * EPT;   // 131072 edges/pass

    int e0 = (blockIdx.x * (THREADS / 16) + team) * EPT;
    int4 s0v, s1v, d0v, d1v, t0v, t1v;
    bool valid = (e0 + EPT <= n_edges);
    if (valid) {
        s0v = *reinterpret_cast<const int4*>(src   + e0);
        s1v = *reinterpret_cast<const int4*>(src   + e0 + 4);
        d0v = *reinterpret_cast<const int4*>(dst   + e0);
        d1v = *reinterpret_cast<const int4*>(dst   + e0 + 4);
        t0v = *reinterpret_cast<const int4*>(etype + e0);
        t1v = *reinterpret_cast<const int4*>(etype + e0 + 4);
    }

    while (valid) {
        // prefetch next iteration's indices (HBM latency hides under the
        // 16 outstanding gathers + compute below)
        const int e1 = e0 + stride;
        const bool nvalid = (e1 + EPT <= n_edges);
        int4 ns0 = s0v, ns1 = s1v, nd0 = d0v, nd1 = d1v, nt0 = t0v, nt1 = t1v;
        if (nvalid) {
            ns0 = *reinterpret_cast<const int4*>(src   + e1);
            ns1 = *reinterpret_cast<const int4*>(src   + e1 + 4);
            nd0 = *reinterpret_cast<const int4*>(dst   + e1);
            nd1 = *reinterpret_cast<const int4*>(dst   + e1 + 4);
            nt0 = *reinterpret_cast<const int4*>(etype + e1);
            nt1 = *reinterpret_cast<const int4*>(etype + e1 + 4);
        }

        // 16 L2 row-gathers in flight: full 256 B fp16 rows, 16 B/lane
        const uint4 a0 = hp[(size_t)(unsigned)s0v.x * 16];
        const uint4 a1 = hp[(size_t)(unsigned)s0v.y * 16];
        const uint4 a2 = hp[(size_t)(unsigned)s0v.z * 16];
        const uint4 a3 = hp[(size_t)(unsigned)s0v.w * 16];
        const uint4 a4 = hp[(size_t)(unsigned)s1v.x * 16];
        const uint4 a5 = hp[(size_t)(unsigned)s1v.y * 16];
        const uint4 a6 = hp[(size_t)(unsigned)s1v.z * 16];
        const uint4 a7 = hp[(size_t)(unsigned)s1v.w * 16];
        const uint4 c0 = hp[(size_t)(unsigned)d0v.x * 16];
        const uint4 c1 = hp[(size_t)(unsigned)d0v.y * 16];
        const uint4 c2 = hp[(size_t)(unsigned)d0v.z * 16];
        const uint4 c3 = hp[(size_t)(unsigned)d0v.w * 16];
        const uint4 c4 = hp[(size_t)(unsigned)d1v.x * 16];
        const uint4 c5 = hp[(size_t)(unsigned)d1v.y * 16];
        const uint4 c6 = hp[(size_t)(unsigned)d1v.z * 16];
        const uint4 c7 = hp[(size_t)(unsigned)d1v.w * 16];

        // quad 0: LDS w reads + dots (while quad-1 gathers still in flight)
        const uint4 b0 = wl[(unsigned)t0v.x * 16];
        const uint4 b1 = wl[(unsigned)t0v.y * 16];
        const uint4 b2 = wl[(unsigned)t0v.z * 16];
        const uint4 b3 = wl[(unsigned)t0v.w * 16];
        float acc0 = dot8(a0, b0, c0);
        float acc1 = dot8(a1, b1, c1);
        float acc2 = dot8(a2, b2, c2);
        float acc3 = dot8(a3, b3, c3);

        // quad 1
        const uint4 b4 = wl[(unsigned)t1v.x * 16];
        const uint4 b5 = wl[(unsigned)t1v.y * 16];
        const uint4 b6 = wl[(unsigned)t1v.z * 16];
        const uint4 b7 = wl[(unsigned)t1v.w * 16];
        float acc4 = dot8(a4, b4, c4);
        float acc5 = dot8(a5, b5, c5);
        float acc6 = dot8(a6, b6, c6);
        float acc7 = dot8(a7, b7, c7);

        acc0 = team_reduce16(acc0);
        acc1 = team_reduce16(acc1);
        acc2 = team_reduce16(acc2);
        acc3 = team_reduce16(acc3);
        acc4 = team_reduce16(acc4);
        acc5 = team_reduce16(acc5);
        acc6 = team_reduce16(acc6);
        acc7 = team_reduce16(acc7);

        if (lane == 0) {
            *reinterpret_cast<float4*>(out + e0) =
                make_float4(acc0, acc1, acc2, acc3);
            *reinterpret_cast<float4*>(out + e0 + 4) =
                make_float4(acc4, acc5, acc6, acc7);
        }

        e0 = e1;
        s0v = ns0; s1v = ns1; d0v = nd0; d1v = nd1; t0v = nt0; t1v = nt1;
        valid = nvalid;
    }

    // tail: fewer than EPT edges left for this team
    for (int e = e0; e < n_edges && e < e0 + EPT; ++e) {
        const uint4 a = hp[(size_t)(unsigned)src[e]   * 16];
        const uint4 c = hp[(size_t)(unsigned)dst[e]   * 16];
        const uint4 b = wl[(unsigned)etype[e] * 16];
        float acc = team_reduce16(dot8(a, b, c));
        if (lane == 0) out[e] = acc;
    }
}

// fallback: fp32 direct if ws too small or n_rels > MAX_RELS
__global__ __launch_bounds__(256) void distmult_score_kernel(
    const float* __restrict__ h,
    const int*   __restrict__ src,
    const int*   __restrict__ dst,
    const int*   __restrict__ etype,
    const float* __restrict__ fwd_rel,
    float*       __restrict__ out,
    int n_edges)
{
    const int tid  = blockIdx.x * blockDim.x + threadIdx.x;
    const int lane = threadIdx.x & 63;
    const int half = lane >> 5;
    const int sub  = lane & 31;
    const int edge = (tid >> 6) * 2 + half;
    if (edge >= n_edges) return;

    const int s = src[edge];
    const int d = dst[edge];
    const int e = etype[edge];

    const float4 a = reinterpret_cast<const float4*>(h       + (size_t)s * EMB_DIM)[sub];
    const float4 b = reinterpret_cast<const float4*>(fwd_rel + (size_t)e * EMB_DIM)[sub];
    const float4 c = reinterpret_cast<const float4*>(h       + (size_t)d * EMB_DIM)[sub];

    float acc = a.x*b.x*c.x + a.y*b.y*c.y + a.z*b.z*c.z + a.w*b.w*c.w;
    #pragma unroll
    for (int off = 16; off > 0; off >>= 1)
        acc += __shfl_down(acc, off, 32);
    if (sub == 0) out[edge] = acc;
}

extern "C" void kernel_launch(void* const* d_in, const int* in_sizes, int n_in,
                              void* d_out, int out_size, void* d_ws, size_t ws_size,
                              hipStream_t stream) {
    const float* h       = (const float*)d_in[0];
    const int*   src     = (const int*)d_in[1];
    const int*   dst     = (const int*)d_in[2];
    const int*   etype   = (const int*)d_in[3];
    const float* fwd_rel = (const float*)d_in[4];
    float* out = (float*)d_out;

    const int n_edges = in_sizes[1];
    const int n_h     = in_sizes[0];              // n_nodes*128
    const int n_w     = in_sizes[4];              // n_rels*128
    const int n_rels  = n_w / EMB_DIM;
    const size_t need = (size_t)(n_h + n_w) * sizeof(u16);

    if (ws_size >= need && n_rels <= MAX_RELS &&
        (n_h % 8) == 0 && (n_w % 8) == 0) {
        u16* h16 = (u16*)d_ws;
        u16* w16 = h16 + n_h;

        const int n_a8 = n_h / 8, n_b8 = n_w / 8;
        const int cgrid = (n_a8 + n_b8 + 255) / 256;
        convert_fp16_kernel<<<cgrid, 256, 0, stream>>>(
            h, h16, n_a8, fwd_rel, w16, n_b8);

        distmult_fp16_kernel<<<BLOCKS, THREADS, 0, stream>>>(
            h16, src, dst, etype, w16, out, n_edges, n_rels);
    } else {
        const int grid = (n_edges + 7) / 8;
        distmult_score_kernel<<<grid, 256, 0, stream>>>(
            h, src, dst, etype, fwd_rel, out, n_edges);
    }
}

// Round 3
// 91.860 us; speedup vs baseline: 1.5933x; 1.4571x over previous
//
#include <hip/hip_runtime.h>
#include <hip/hip_fp16.h>

// DistMult forward scoring: score[e] = sum_d h[src,d] * fwd_rel[et,d] * h[dst,d]
// E=640000, D=128, fp32 in/out.
//
// R7: revert R6's EPT=8 unroll (VGPR spill: FETCH 83MB/WRITE 115MB of
// scratch traffic, main 66us). Restore the proven R4 shape: EPT=4, 8
// row-gathers in flight, fp16 h table in ws (L2-resident), fp16 fwd_rel in
// LDS, plain __launch_bounds__(1024) (no min-wave hint -> 52-VGPR no-spill
// codegen). Kept from R5/R6: v_pk_mul_f16 + v_fma_mix_f32 dot math and
// next-iteration INDEX prefetch only (12 extra VGPRs, takes the ~900cy cold
// HBM index read off the critical chain). Main floor: 328 MB L2 gather
// delivery at ~15 TB/s ~= 22-26 us; total floor ~= 42us ws-poison + ~20us
// dispatch overhead + main + ~4us convert.

typedef unsigned short u16;
typedef _Float16 h2v __attribute__((ext_vector_type(2)));

constexpr int EMB_DIM  = 128;
constexpr int MAX_RELS = 500;
constexpr int BLOCKS   = 256;    // 1 per CU
constexpr int THREADS  = 1024;   // 64 teams of 16 lanes

// ---- fp32 -> fp16 pack, 8 floats per slot ----
__device__ __forceinline__ void convert_slot(const float* __restrict__ s,
                                             u16* __restrict__ d, int j) {
    float4 lo = reinterpret_cast<const float4*>(s)[j * 2];
    float4 hi = reinterpret_cast<const float4*>(s)[j * 2 + 1];
    u16 u0 = __half_as_ushort(__float2half(lo.x));
    u16 u1 = __half_as_ushort(__float2half(lo.y));
    u16 u2 = __half_as_ushort(__float2half(lo.z));
    u16 u3 = __half_as_ushort(__float2half(lo.w));
    u16 u4 = __half_as_ushort(__float2half(hi.x));
    u16 u5 = __half_as_ushort(__float2half(hi.y));
    u16 u6 = __half_as_ushort(__float2half(hi.z));
    u16 u7 = __half_as_ushort(__float2half(hi.w));
    uint4 v;
    v.x = (unsigned)u0 | ((unsigned)u1 << 16);
    v.y = (unsigned)u2 | ((unsigned)u3 << 16);
    v.z = (unsigned)u4 | ((unsigned)u5 << 16);
    v.w = (unsigned)u6 | ((unsigned)u7 << 16);
    reinterpret_cast<uint4*>(d)[j] = v;
}

__global__ __launch_bounds__(256) void convert_fp16_kernel(
    const float* __restrict__ a, u16* __restrict__ a16, int n_a8,
    const float* __restrict__ b, u16* __restrict__ b16, int n_b8)
{
    const int total = n_a8 + n_b8;
    for (int i = blockIdx.x * blockDim.x + threadIdx.x; i < total;
         i += gridDim.x * blockDim.x) {
        if (i < n_a8) convert_slot(a, a16, i);
        else          convert_slot(b, b16, i - n_a8);
    }
}

// 8-element triple product, f32 accumulate.
// t = a*c packed fp16 (v_pk_mul_f16); (float)t * (float)b + acc folds to
// v_fma_mix_f32. ~12 VALU per dot8.
__device__ __forceinline__ float dot8(uint4 A, uint4 B, uint4 C) {
    const h2v* a = reinterpret_cast<const h2v*>(&A);
    const h2v* b = reinterpret_cast<const h2v*>(&B);
    const h2v* c = reinterpret_cast<const h2v*>(&C);
    float acc = 0.f;
    #pragma unroll
    for (int k = 0; k < 4; ++k) {
        h2v t = a[k] * c[k];                    // v_pk_mul_f16
        acc += (float)t.x * (float)b[k].x;      // v_fma_mix_f32
        acc += (float)t.y * (float)b[k].y;      // v_fma_mix_f32
    }
    return acc;
}

__device__ __forceinline__ float team_reduce16(float acc) {
    #pragma unroll
    for (int off = 8; off > 0; off >>= 1)
        acc += __shfl_down(acc, off, 16);
    return acc;
}

__global__ __launch_bounds__(THREADS) void distmult_fp16_kernel(
    const u16* __restrict__ h16,     // [n_nodes][128] fp16
    const int* __restrict__ src,
    const int* __restrict__ dst,
    const int* __restrict__ etype,
    const u16* __restrict__ w16,     // [n_rels][128] fp16
    float*     __restrict__ out,
    int n_edges, int n_rels)
{
    __shared__ u16 w_lds[MAX_RELS * EMB_DIM];   // 128 KB

    // stage fwd_rel fp16 into LDS (linear, coalesced uint4)
    {
        const int slots = n_rels * (EMB_DIM / 8);
        for (int s = threadIdx.x; s < slots; s += THREADS)
            reinterpret_cast<uint4*>(w_lds)[s] =
                reinterpret_cast<const uint4*>(w16)[s];
    }
    __syncthreads();

    const int team = threadIdx.x >> 4;   // 64 teams
    const int lane = threadIdx.x & 15;

    const uint4* hp = reinterpret_cast<const uint4*>(h16) + lane;  // +16/row
    const uint4* wl = reinterpret_cast<const uint4*>(w_lds) + lane;

    const int stride = BLOCKS * (THREADS / 16) * 4;   // 65536 edges/pass

    int e0 = (blockIdx.x * (THREADS / 16) + team) * 4;
    int4 s4, d4, t4;
    bool valid = (e0 + 3 < n_edges);
    if (valid) {
        s4 = *reinterpret_cast<const int4*>(src   + e0);
        d4 = *reinterpret_cast<const int4*>(dst   + e0);
        t4 = *reinterpret_cast<const int4*>(etype + e0);
    }

    while (valid) {
        // prefetch next iteration's indices: takes the cold HBM index read
        // off the critical chain (hides under the 8 gathers + compute)
        const int e1 = e0 + stride;
        const bool nvalid = (e1 + 3 < n_edges);
        int4 ns = s4, nd = d4, nt = t4;
        if (nvalid) {
            ns = *reinterpret_cast<const int4*>(src   + e1);
            nd = *reinterpret_cast<const int4*>(dst   + e1);
            nt = *reinterpret_cast<const int4*>(etype + e1);
        }

        // 8 L2 gathers in flight: full 256 B fp16 rows, 16 B/lane
        const uint4 a0 = hp[(size_t)(unsigned)s4.x * 16];
        const uint4 a1 = hp[(size_t)(unsigned)s4.y * 16];
        const uint4 a2 = hp[(size_t)(unsigned)s4.z * 16];
        const uint4 a3 = hp[(size_t)(unsigned)s4.w * 16];
        const uint4 c0 = hp[(size_t)(unsigned)d4.x * 16];
        const uint4 c1 = hp[(size_t)(unsigned)d4.y * 16];
        const uint4 c2 = hp[(size_t)(unsigned)d4.z * 16];
        const uint4 c3 = hp[(size_t)(unsigned)d4.w * 16];
        // 4 LDS reads for w
        const uint4 b0 = wl[(unsigned)t4.x * 16];
        const uint4 b1 = wl[(unsigned)t4.y * 16];
        const uint4 b2 = wl[(unsigned)t4.z * 16];
        const uint4 b3 = wl[(unsigned)t4.w * 16];

        float acc0 = dot8(a0, b0, c0);
        float acc1 = dot8(a1, b1, c1);
        float acc2 = dot8(a2, b2, c2);
        float acc3 = dot8(a3, b3, c3);

        acc0 = team_reduce16(acc0);
        acc1 = team_reduce16(acc1);
        acc2 = team_reduce16(acc2);
        acc3 = team_reduce16(acc3);

        if (lane == 0)
            *reinterpret_cast<float4*>(out + e0) =
                make_float4(acc0, acc1, acc2, acc3);

        e0 = e1; s4 = ns; d4 = nd; t4 = nt; valid = nvalid;
    }

    // tail: fewer than 4 edges left for this team
    for (int e = e0; e < n_edges && e < e0 + 4; ++e) {
        const uint4 a = hp[(size_t)(unsigned)src[e]   * 16];
        const uint4 c = hp[(size_t)(unsigned)dst[e]   * 16];
        const uint4 b = wl[(unsigned)etype[e] * 16];
        float acc = team_reduce16(dot8(a, b, c));
        if (lane == 0) out[e] = acc;
    }
}

// fallback: fp32 direct if ws too small or n_rels > MAX_RELS
__global__ __launch_bounds__(256) void distmult_score_kernel(
    const float* __restrict__ h,
    const int*   __restrict__ src,
    const int*   __restrict__ dst,
    const int*   __restrict__ etype,
    const float* __restrict__ fwd_rel,
    float*       __restrict__ out,
    int n_edges)
{
    const int tid  = blockIdx.x * blockDim.x + threadIdx.x;
    const int lane = threadIdx.x & 63;
    const int half = lane >> 5;
    const int sub  = lane & 31;
    const int edge = (tid >> 6) * 2 + half;
    if (edge >= n_edges) return;

    const int s = src[edge];
    const int d = dst[edge];
    const int e = etype[edge];

    const float4 a = reinterpret_cast<const float4*>(h       + (size_t)s * EMB_DIM)[sub];
    const float4 b = reinterpret_cast<const float4*>(fwd_rel + (size_t)e * EMB_DIM)[sub];
    const float4 c = reinterpret_cast<const float4*>(h       + (size_t)d * EMB_DIM)[sub];

    float acc = a.x*b.x*c.x + a.y*b.y*c.y + a.z*b.z*c.z + a.w*b.w*c.w;
    #pragma unroll
    for (int off = 16; off > 0; off >>= 1)
        acc += __shfl_down(acc, off, 32);
    if (sub == 0) out[edge] = acc;
}

extern "C" void kernel_launch(void* const* d_in, const int* in_sizes, int n_in,
                              void* d_out, int out_size, void* d_ws, size_t ws_size,
                              hipStream_t stream) {
    const float* h       = (const float*)d_in[0];
    const int*   src     = (const int*)d_in[1];
    const int*   dst     = (const int*)d_in[2];
    const int*   etype   = (const int*)d_in[3];
    const float* fwd_rel = (const float*)d_in[4];
    float* out = (float*)d_out;

    const int n_edges = in_sizes[1];
    const int n_h     = in_sizes[0];              // n_nodes*128
    const int n_w     = in_sizes[4];              // n_rels*128
    const int n_rels  = n_w / EMB_DIM;
    const size_t need = (size_t)(n_h + n_w) * sizeof(u16);

    if (ws_size >= need && n_rels <= MAX_RELS &&
        (n_h % 8) == 0 && (n_w % 8) == 0) {
        u16* h16 = (u16*)d_ws;
        u16* w16 = h16 + n_h;

        const int n_a8 = n_h / 8, n_b8 = n_w / 8;
        const int cgrid = (n_a8 + n_b8 + 255) / 256;
        convert_fp16_kernel<<<cgrid, 256, 0, stream>>>(
            h, h16, n_a8, fwd_rel, w16, n_b8);

        distmult_fp16_kernel<<<BLOCKS, THREADS, 0, stream>>>(
            h16, src, dst, etype, w16, out, n_edges, n_rels);
    } else {
        const int grid = (n_edges + 7) / 8;
        distmult_score_kernel<<<grid, 256, 0, stream>>>(
            h, src, dst, etype, fwd_rel, out, n_edges);
    }
}